// Round 1
// 642.227 us; speedup vs baseline: 3.4017x; 3.4017x over previous
//
#include <hip/hip_runtime.h>
#include <cstdint>
#include <cstddef>

// ---------------------------------------------------------------------------
// Residual VQ (SoundStream Alg.1) on MI355X — R4: MFMA rewrite.
// R3 was a pure fp32-VALU GEMM: MfmaUtil 0, VALUBusy 56%, structurally capped
// near the 157 TF fp32 ceiling (~874 us of FMA issue alone). R4 moves the
// distance GEMM to the f16 matrix pipe (v_mfma_f32_32x32x16_f16, 2.4 PF):
//  - 256 WGs (1/CU) x 512 thr; 64 pts/WG; residual fp32 in REGISTERS (64/thr)
//  - f16 A-plane in LDS (64 KB, swap3^row XOR swizzle -> conflict-free b128)
//  - codebook pre-converted to f16 chunk images (k_prep, 8.4 MB ws); staged
//    32 KB/K-step via global_load_lds, double-buffered, counted vmcnt(4) +
//    raw s_barrier (never drain mid-loop)
//  - exactness preserved: f16 scores only SELECT candidates (margin 1.5 vs
//    error sigma~0.03); tier-1 = fp64 dot vs exact fp32 residual (regs);
//    tier-2 = fp64 chain rebuild from x for <1e-3 gaps. Emitted indices are
//    the exact-arithmetic argmin, same as the passing R3. Residual update,
//    commit loss (fp64) and outputs are bit-identical logic to R3.
// ---------------------------------------------------------------------------

#define BATCH 8
#define SEQ   2048
#define DIM   512
#define NUMQ  8
#define CODES 1024
#define NPTS  (BATCH*SEQ)            // 16384
#define MPTS  64                     // points per workgroup
#define NWG   (NPTS/MPTS)            // 256 = 1 WG per CU
#define NTHR  512
#define NCHUNK 32                    // K-steps of 16 per quantizer
#define CHUNK_BYTES 32768            // [g:2][code:1024][8 f16] = 32 KB

#define OUT_IDX   (BATCH*SEQ*DIM)             // 8388608
#define OUT_LOSS  (OUT_IDX + BATCH*SEQ*NUMQ)  // 8519680

#define WS_LOSS   0                           // 8 doubles
#define WS_CNORM  1024                        // 8192 floats
#define WS_CBH    40960                       // f16 chunk images, 8.39 MB

typedef _Float16 f16x8  __attribute__((ext_vector_type(8)));
typedef _Float16 f16x4  __attribute__((ext_vector_type(4)));
typedef float    f32x16 __attribute__((ext_vector_type(16)));

__global__ void k_zero(double* loss) {
  if (threadIdx.x < NUMQ) loss[threadIdx.x] = 0.0;
}

// per-code squared norm (fp32; only feeds the approximate scores)
__global__ void k_cnorm(const float* __restrict__ cb, float* __restrict__ cnorm) {
  int r = blockIdx.x * blockDim.x + threadIdx.x;      // 0..8191
  const float* row = cb + (size_t)r * DIM;
  float s = 0.f;
  for (int d = 0; d < DIM; d += 4) {
    float4 v = *(const float4*)(row + d);
    s += v.x * v.x + v.y * v.y + v.z * v.z + v.w * v.w;
  }
  cnorm[r] = s;
}

// Build f16 codebook chunk images. Chunk (q,ks) image (32 KB, linear):
//   byte = g*16384 + c*16 + j*2  holds  f16(cb[q][c][ks*16 + g*8 + j])
// so a linear global_load_lds stage gives each lane (col=l&31,kgrp=l>>5) its
// 16B B-fragment (8 consecutive k) with one ds_read_b128, conflict-free.
__global__ void k_prep(const float* __restrict__ cb, unsigned char* __restrict__ cbH) {
  unsigned tid = blockIdx.x * blockDim.x + threadIdx.x;   // 0..1048575 (8B units)
  unsigned h  = tid & 1;
  unsigned r  = tid >> 1;
  unsigned c  = r & (CODES - 1);
  unsigned t2 = r >> 10;
  unsigned g  = t2 & 1;
  unsigned t3 = t2 >> 1;
  unsigned ks = t3 & 31;
  unsigned q  = t3 >> 5;
  unsigned k  = ks * 16 + g * 8 + h * 4;
  float4 v = *(const float4*)(cb + ((size_t)((q << 10) | c)) * DIM + k);
  f16x4 o;
  o[0] = (_Float16)v.x; o[1] = (_Float16)v.y; o[2] = (_Float16)v.z; o[3] = (_Float16)v.w;
  *(f16x4*)(cbH + (size_t)tid * 8) = o;
}

// issue one 32 KB chunk stage (4x global_load_lds dwordx4 per thread)
__device__ __forceinline__ void stage(const unsigned char* __restrict__ cbq, int ks,
                                      unsigned char* buf, int tid) {
  const unsigned char* src = cbq + (size_t)ks * CHUNK_BYTES + tid * 16;
  unsigned char* dst = buf + (tid & ~63) * 16;   // wave-uniform base; HW adds lane*16
  #pragma unroll
  for (int i = 0; i < 4; ++i)
    __builtin_amdgcn_global_load_lds(
        (const __attribute__((address_space(1))) void*)(src + i * 8192),
        (__attribute__((address_space(3))) void*)(dst + i * 8192), 16, 0, 0);
}

__launch_bounds__(NTHR, 2)
__global__ void k_main(const float* __restrict__ x, const float* __restrict__ cb,
                       const unsigned char* __restrict__ cbH,
                       const float* __restrict__ cnorm,
                       double* __restrict__ lossAcc,
                       float* __restrict__ out)
{
  // A-plane: f16 resid, row m (64) x 512 k. 16B slot s=k/8 stored at
  // slot' = swap3(s) ^ (m&31)  (swap3 swaps the two 3-bit halves) ->
  // conflict-free on BOTH the b128 frag reads and the b128 build writes.
  __shared__ __align__(16) unsigned char Af[MPTS * DIM * 2];      // 64 KB
  __shared__ __align__(16) unsigned char Bb[2][CHUNK_BYTES];      // 64 KB
  __shared__ float          s1w[MPTS][8];
  __shared__ unsigned short id1w[MPTS][8];
  __shared__ unsigned short cand[MPTS][8][4];
  __shared__ unsigned char  ccnt[MPTS][8];
  __shared__ float          gmA[MPTS];
  __shared__ int            win0A[MPTS];
  __shared__ unsigned short idxs[MPTS][NUMQ];
  __shared__ double         lred[8];

  const int tid = threadIdx.x;
  const int cl  = tid & 63;
  const int w   = tid >> 6;          // wave 0..7
  const int l31 = cl & 31;
  const int l5  = cl >> 5;           // k-group within wave
  const int wg  = blockIdx.x;

  // residual registers: thread owns point rp = tid>>3, dims rj*64..+64
  const int rp = tid >> 3;
  const int rj = tid & 7;
  const size_t gp = (size_t)wg * MPTS + rp;
  float4 r4[16];
  {
    const float4* xr = (const float4*)(x + gp * DIM + rj * 64);
    #pragma unroll
    for (int i = 0; i < 16; ++i) r4[i] = xr[i];
  }

  const int bBase = l5 * 16384 + (w * 128 + l31) * 16;  // B frag byte (within buf)

  for (int q = 0; q < NUMQ; ++q) {
    // ---- A-plane build: f16(resid), swizzled (write columns j^.., c-free)
    #pragma unroll
    for (int i = 0; i < 8; ++i) {
      float4 a = r4[2 * i], b = r4[2 * i + 1];
      f16x8 v;
      v[0] = (_Float16)a.x; v[1] = (_Float16)a.y; v[2] = (_Float16)a.z; v[3] = (_Float16)a.w;
      v[4] = (_Float16)b.x; v[5] = (_Float16)b.y; v[6] = (_Float16)b.z; v[7] = (_Float16)b.w;
      int sl = ((i << 3) | rj) ^ (rp & 31);            // swap3(j*8+i) ^ row
      *(f16x8*)(Af + rp * 1024 + (sl << 4)) = v;
    }
    __syncthreads();

    const unsigned char* cbq = cbH + (size_t)q * NCHUNK * CHUNK_BYTES;
    stage(cbq, 0, Bb[0], tid);
    stage(cbq, 1, Bb[1], tid);

    f32x16 acc[2][4];
    #pragma unroll
    for (int mt = 0; mt < 2; ++mt)
      #pragma unroll
      for (int nt = 0; nt < 4; ++nt)
        #pragma unroll
        for (int e = 0; e < 16; ++e) acc[mt][nt][e] = 0.0f;

    // ---- MFMA K-loop: counted vmcnt, raw barriers, dbuf staging
    #pragma unroll 1
    for (int ks = 0; ks < NCHUNK; ++ks) {
      if (ks < NCHUNK - 1) asm volatile("s_waitcnt vmcnt(4)" ::: "memory");
      else                 asm volatile("s_waitcnt vmcnt(0)" ::: "memory");
      __builtin_amdgcn_s_barrier();                    // chunk ks fully staged
      const unsigned char* bufp = Bb[ks & 1];
      const int s5 = (ks << 1) | l5;
      const int sf = ((((s5 & 7) << 3) | (s5 >> 3)) ^ l31) << 4;
      f16x8 a0 = *(const f16x8*)(Af + l31 * 1024 + sf);
      f16x8 a1 = *(const f16x8*)(Af + 32768 + l31 * 1024 + sf);
      f16x8 b0 = *(const f16x8*)(bufp + bBase);
      f16x8 b1 = *(const f16x8*)(bufp + bBase + 512);
      f16x8 b2 = *(const f16x8*)(bufp + bBase + 1024);
      f16x8 b3 = *(const f16x8*)(bufp + bBase + 1536);
      __builtin_amdgcn_s_setprio(1);
      acc[0][0] = __builtin_amdgcn_mfma_f32_32x32x16_f16(a0, b0, acc[0][0], 0, 0, 0);
      acc[0][1] = __builtin_amdgcn_mfma_f32_32x32x16_f16(a0, b1, acc[0][1], 0, 0, 0);
      acc[0][2] = __builtin_amdgcn_mfma_f32_32x32x16_f16(a0, b2, acc[0][2], 0, 0, 0);
      acc[0][3] = __builtin_amdgcn_mfma_f32_32x32x16_f16(a0, b3, acc[0][3], 0, 0, 0);
      acc[1][0] = __builtin_amdgcn_mfma_f32_32x32x16_f16(a1, b0, acc[1][0], 0, 0, 0);
      acc[1][1] = __builtin_amdgcn_mfma_f32_32x32x16_f16(a1, b1, acc[1][1], 0, 0, 0);
      acc[1][2] = __builtin_amdgcn_mfma_f32_32x32x16_f16(a1, b2, acc[1][2], 0, 0, 0);
      acc[1][3] = __builtin_amdgcn_mfma_f32_32x32x16_f16(a1, b3, acc[1][3], 0, 0, 0);
      __builtin_amdgcn_s_setprio(0);
      asm volatile("s_waitcnt lgkmcnt(0)" ::: "memory");
      __builtin_amdgcn_s_barrier();                    // all reads of buf done
      if (ks + 2 < NCHUNK) stage(cbq, ks + 2, (unsigned char*)Bb[ks & 1], tid);
    }

    // ---- scores = -2*dot + ||c||^2 (approximate; f16-rounded inputs)
    {
      const float* cnq = cnorm + (q << 10) + (w << 7) + l31;
      const float cn0 = cnq[0], cn1 = cnq[32], cn2 = cnq[64], cn3 = cnq[96];
      #pragma unroll
      for (int mt = 0; mt < 2; ++mt) {
        acc[mt][0] = acc[mt][0] * -2.0f + cn0;
        acc[mt][1] = acc[mt][1] * -2.0f + cn1;
        acc[mt][2] = acc[mt][2] * -2.0f + cn2;
        acc[mt][3] = acc[mt][3] * -2.0f + cn3;
      }
    }

    // ---- pass 1: per-wave per-point top-1 (over this wave's 128 codes)
    // C/D layout 32x32: col = lane&31, row = (r&3)+8*(r>>2)+4*(lane>>5)
    #pragma unroll
    for (int mt = 0; mt < 2; ++mt)
      #pragma unroll
      for (int r = 0; r < 16; ++r) {
        float s = acc[mt][0][r]; int bi = l31;
        if (acc[mt][1][r] < s) { s = acc[mt][1][r]; bi = 32 + l31; }
        if (acc[mt][2][r] < s) { s = acc[mt][2][r]; bi = 64 + l31; }
        if (acc[mt][3][r] < s) { s = acc[mt][3][r]; bi = 96 + l31; }
        #pragma unroll
        for (int m = 1; m < 32; m <<= 1) {
          float os = __shfl_xor(s, m); int ob = __shfl_xor(bi, m);
          if (os < s || (os == s && ob < bi)) { s = os; bi = ob; }
        }
        if (l31 == 0) {
          int p = mt * 32 + (r & 3) + 8 * (r >> 2) + 4 * l5;
          s1w[p][w] = s; id1w[p][w] = (unsigned short)bi;
        }
      }
    __syncthreads();

    // ---- pass 2: global min + provisional winner per point
    if (tid < MPTS) {
      int p = tid;
      float bs = s1w[p][0]; int bi = id1w[p][0];
      #pragma unroll
      for (int ww = 1; ww < 8; ++ww) {
        float s = s1w[p][ww];
        if (s < bs) { bs = s; bi = ww * 128 + id1w[p][ww]; }
      }
      gmA[p] = bs; win0A[p] = bi;
    }
    __syncthreads();

    // ---- pass 3: ballot candidates within margin of global min
    #pragma unroll
    for (int mt = 0; mt < 2; ++mt)
      #pragma unroll
      for (int r = 0; r < 16; ++r) {
        const int p0 = mt * 32 + (r & 3) + 8 * (r >> 2);
        const float g0 = gmA[p0], g1 = gmA[p0 + 4];
        const float lim0 = g0 + 1.5f + 1e-4f * fabsf(g0);
        const float lim1 = g1 + 1.5f + 1e-4f * fabsf(g1);
        const float lim = l5 ? lim1 : lim0;
        unsigned long long b0 = __ballot(acc[mt][0][r] <= lim);
        unsigned long long b1 = __ballot(acc[mt][1][r] <= lim);
        unsigned long long b2 = __ballot(acc[mt][2][r] <= lim);
        unsigned long long b3 = __ballot(acc[mt][3][r] <= lim);
        if (cl == 0 || cl == 32) {
          const int p = p0 + (cl >> 3);
          unsigned short* cd = &cand[p][w][0];
          unsigned m0 = (cl == 0) ? (unsigned)b0 : (unsigned)(b0 >> 32);
          unsigned m1 = (cl == 0) ? (unsigned)b1 : (unsigned)(b1 >> 32);
          unsigned m2 = (cl == 0) ? (unsigned)b2 : (unsigned)(b2 >> 32);
          unsigned m3 = (cl == 0) ? (unsigned)b3 : (unsigned)(b3 >> 32);
          int n = 0;
          while (m0 && n < 4) { int bt = __builtin_ctz(m0); m0 &= m0 - 1; cd[n++] = (unsigned short)(bt); }
          while (m1 && n < 4) { int bt = __builtin_ctz(m1); m1 &= m1 - 1; cd[n++] = (unsigned short)(32 + bt); }
          while (m2 && n < 4) { int bt = __builtin_ctz(m2); m2 &= m2 - 1; cd[n++] = (unsigned short)(64 + bt); }
          while (m3 && n < 4) { int bt = __builtin_ctz(m3); m3 &= m3 - 1; cd[n++] = (unsigned short)(96 + bt); }
          ccnt[p][w] = (unsigned char)n;
        }
      }
    __syncthreads();

    // ---- pass 4: refinement tiers (wave w owns points w*8..w*8+7; their
    //      fp32 residual lives in this wave's r4 registers)
    #pragma unroll 1
    for (int pp = 0; pp < 8; ++pp) {
      const int p = w * 8 + pp;
      int tot = 0;
      #pragma unroll
      for (int ww = 0; ww < 8; ++ww) tot += ccnt[p][ww];
      int winner;
      if (tot <= 1) {
        winner = win0A[p];
      } else {
        const size_t gpp = (size_t)wg * MPTS + p;
        // tier 1: fp64 dot vs exact fp32 residual (in regs)
        double bs = 1.0e300, bs2 = 1.0e300; int bi = 0x7FFFFFFF;
        #pragma unroll 1
        for (int ww = 0; ww < 8; ++ww) {
          const int nn = ccnt[p][ww];
          #pragma unroll 1
          for (int si = 0; si < nn; ++si) {
            const int cc = ww * 128 + cand[p][ww][si];
            const float4* cr = (const float4*)(cb + ((size_t)q * CODES + cc) * DIM + (cl & 7) * 64);
            double dt = 0.0, cs = 0.0;
            #pragma unroll
            for (int i = 0; i < 16; ++i) {
              float4 cv = cr[i];
              dt += (double)r4[i].x * cv.x + (double)r4[i].y * cv.y
                  + (double)r4[i].z * cv.z + (double)r4[i].w * cv.w;
              cs += (double)cv.x * cv.x + (double)cv.y * cv.y
                  + (double)cv.z * cv.z + (double)cv.w * cv.w;
            }
            #pragma unroll
            for (int m = 1; m < 8; m <<= 1) { dt += __shfl_xor(dt, m); cs += __shfl_xor(cs, m); }
            double dtb = __shfl(dt, pp * 8), csb = __shfl(cs, pp * 8);
            double s = -2.0 * dtb + csb;
            if (s < bs) { bs2 = bs; bs = s; bi = cc; }
            else if (s < bs2) { bs2 = s; }
          }
        }
        // tier 2: exact fp64 chain rebuild from x (rare: <1e-3 gap)
        if (bs2 - bs <= 1e-3 + 1e-6 * fabs(bs)) {
          bs = 1.0e300; bi = 0x7FFFFFFF;
          const float4* xr2 = (const float4*)(x + gpp * DIM + (cl & 7) * 64);
          #pragma unroll 1
          for (int ww = 0; ww < 8; ++ww) {
            const int nn = ccnt[p][ww];
            #pragma unroll 1
            for (int si = 0; si < nn; ++si) {
              const int cc = ww * 128 + cand[p][ww][si];
              const float4* cr = (const float4*)(cb + ((size_t)q * CODES + cc) * DIM + (cl & 7) * 64);
              double dt = 0.0, cs = 0.0;
              #pragma unroll 1
              for (int i = 0; i < 16; ++i) {
                float4 xv = xr2[i];
                double rhx = xv.x, rhy = xv.y, rhz = xv.z, rhw = xv.w;
                #pragma unroll 1
                for (int t2 = 0; t2 < q; ++t2) {
                  const float4* qr = (const float4*)(cb + ((size_t)t2 * CODES + idxs[p][t2]) * DIM + (cl & 7) * 64);
                  float4 qv = qr[i];
                  rhx -= (double)qv.x; rhy -= (double)qv.y;
                  rhz -= (double)qv.z; rhw -= (double)qv.w;
                }
                float4 cv = cr[i];
                dt += rhx * cv.x + rhy * cv.y + rhz * cv.z + rhw * cv.w;
                cs += (double)cv.x * cv.x + (double)cv.y * cv.y
                    + (double)cv.z * cv.z + (double)cv.w * cv.w;
              }
              #pragma unroll
              for (int m = 1; m < 8; m <<= 1) { dt += __shfl_xor(dt, m); cs += __shfl_xor(cs, m); }
              double dtb = __shfl(dt, pp * 8), csb = __shfl(cs, pp * 8);
              double s = -2.0 * dtb + csb;
              if (s < bs || (s == bs && cc < bi)) { bs = s; bi = cc; }
            }
          }
        }
        winner = bi;
      }
      if (cl == 0) idxs[p][q] = (unsigned short)winner;
    }

    // ---- pass 5: residual update (exact fp32 chain) + commit loss (fp64)
    {
      const int win = idxs[rp][q];
      const float4* cr = (const float4*)(cb + ((size_t)q * CODES + win) * DIM + rj * 64);
      double ls = 0.0;
      #pragma unroll
      for (int i = 0; i < 16; ++i) {
        float4 cv = cr[i];
        float dx = cv.x - r4[i].x, dy = cv.y - r4[i].y;
        float dz = cv.z - r4[i].z, dw = cv.w - r4[i].w;
        ls += (double)dx * dx + (double)dy * dy + (double)dz * dz + (double)dw * dw;
        r4[i].x -= cv.x; r4[i].y -= cv.y; r4[i].z -= cv.z; r4[i].w -= cv.w;
      }
      #pragma unroll
      for (int m = 1; m < 64; m <<= 1) ls += __shfl_xor(ls, m);
      if (cl == 0) lred[w] = ls;
      __syncthreads();
      if (tid == 0) {
        double t = lred[0] + lred[1] + lred[2] + lred[3]
                 + lred[4] + lred[5] + lred[6] + lred[7];
        atomicAdd(lossAcc + q, t);
      }
    }
  } // q

  // ---- outputs: quantized = x - resid_final; indices as float
  {
    const float4* xr = (const float4*)(x + gp * DIM + rj * 64);
    float4* orow = (float4*)(out + gp * DIM + rj * 64);
    #pragma unroll
    for (int i = 0; i < 16; ++i) {
      float4 xv = xr[i];
      float4 o;
      o.x = xv.x - r4[i].x; o.y = xv.y - r4[i].y;
      o.z = xv.z - r4[i].z; o.w = xv.w - r4[i].w;
      orow[i] = o;
    }
  }
  if (tid < MPTS) {
    float* ob = out + OUT_IDX + ((size_t)wg * MPTS + tid) * NUMQ;
    #pragma unroll
    for (int j = 0; j < NUMQ; ++j) ob[j] = (float)idxs[tid][j];
  }
}

__global__ void k_fin(const double* __restrict__ loss, float* __restrict__ out) {
  int t = threadIdx.x;
  if (t < NUMQ)
    out[OUT_LOSS + t] = (float)(loss[t] / (double)((size_t)BATCH * SEQ * DIM));
}

extern "C" void kernel_launch(void* const* d_in, const int* in_sizes, int n_in,
                              void* d_out, int out_size, void* d_ws, size_t ws_size,
                              hipStream_t stream) {
  (void)in_sizes; (void)n_in; (void)out_size; (void)ws_size;
  const float* x  = (const float*)d_in[0];
  const float* cb = (const float*)d_in[1];
  float* out = (float*)d_out;
  char* ws = (char*)d_ws;
  double* loss = (double*)(ws + WS_LOSS);
  float* cnorm = (float*)(ws + WS_CNORM);
  unsigned char* cbH = (unsigned char*)(ws + WS_CBH);   // 8.39 MB (< old 16.8 MB use)

  k_zero<<<1, 64, 0, stream>>>(loss);
  k_cnorm<<<NUMQ * CODES / 256, 256, 0, stream>>>(cb, cnorm);
  k_prep<<<NUMQ * NCHUNK * CHUNK_BYTES / 8 / 256, 256, 0, stream>>>(cb, cbH);
  k_main<<<NWG, NTHR, 0, stream>>>(x, cb, cbH, cnorm, loss, out);
  k_fin<<<1, 64, 0, stream>>>(loss, out);
}